// Round 9
// baseline (127.479 us; speedup 1.0000x reference)
//
#include <hip/hip_runtime.h>

#define SEQ    1024
#define BATCH  512
#define NTAGS  48
#define CH     8

// Bidirectional split across waves (r8 structure): blocks 0..511 forward
// alpha (t=1..511), blocks 512..1023 backward beta (u=1023..512).
// NEW: hybrid broadcast per step -- k=0..23 via LDS (ds_write + 6 uniform
// ds_read_b128, broadcast on the DS pipe) overlapped with k=24..47 via 24
// readlanes (r6 3-group schedule). The two paths run on independent pipes,
// cutting the ~240cy readlane-stream stall. Renorm pivot a[0] comes from the
// first LDS read. Numerator moved to the backward blocks (load balance).
__global__ __launch_bounds__(64) void crf_dir_kernel(
    const float* __restrict__ em,     // [SEQ,BATCH,NTAGS] f32
    const int*   __restrict__ tags,   // [SEQ,BATCH] int32
    const int*   __restrict__ mask,   // [SEQ,BATCH] int32
    const float* __restrict__ start_t,
    const float* __restrict__ end_t,
    const float* __restrict__ trans,  // [NTAGS,NTAGS]
    float*       __restrict__ alpha,  // [BATCH,NTAGS]
    float*       __restrict__ beta,   // [BATCH,NTAGS]
    float*       __restrict__ cfb,    // [BATCH]
    float*       __restrict__ cbb,    // [BATCH]
    float*       __restrict__ numb)   // [BATCH]
{
  const int bid  = blockIdx.x;
  const int b    = bid & (BATCH - 1);
  const int dir  = bid >> 9;             // 0 = forward, 1 = backward
  const int lane = threadIdx.x;
  const bool act = lane < NTAGS;
  const int jj   = act ? lane : 0;

  __shared__ __align__(16) float sa[64];
  __shared__ int smask[SEQ];

  int myall = 1;
#pragma unroll
  for (int k = 0; k < SEQ / 64; ++k) {
    int t = lane + 64 * k;
    int v = mask[(size_t)t * BATCH + b];
    smask[t] = v;
    myall &= (v != 0) ? 1 : 0;
  }
  const bool allones = (__ballot(myall) == ~0ull);

  const size_t strideT = (size_t)BATCH * NTAGS;
  const float* emcol   = em + (size_t)b * NTAGS + jj;

#define RLX(x, k) __int_as_float(__builtin_amdgcn_readlane(__float_as_int(x), (k)))

#define LOADCH(R, ci) do {                                            \
    const float* pp_ = emcol + (size_t)(ci) * CH * strideT;           \
    _Pragma("unroll")                                                 \
    for (int p_ = 0; p_ < CH; ++p_)                                   \
      (R)[p_] = pp_[(size_t)p_ * strideT];                            \
  } while (0)

  // 4 LDS-sourced FMAs: float4 V covers wcol indices B..B+3
#define LDSF(V, B, WARR) do {                                         \
    acc_[((B) + 0) & 7] = fmaf((V).x, WARR[(B) + 0], acc_[((B) + 0) & 7]); \
    acc_[((B) + 1) & 7] = fmaf((V).y, WARR[(B) + 1], acc_[((B) + 1) & 7]); \
    acc_[((B) + 2) & 7] = fmaf((V).z, WARR[(B) + 2], acc_[((B) + 2) & 7]); \
    acc_[((B) + 3) & 7] = fmaf((V).w, WARR[(B) + 3], acc_[((B) + 3) & 7]); \
  } while (0)

  // Hybrid matvec core: broadcasts XV (per-lane value, lanes 0..47 valid),
  // dots with WARR. Leaves sum in S_OUT, pre-update pivot (XV at lane 0)
  // in PV_OUT.
#define HCORE(XV, WARR, S_OUT, PV_OUT) do {                           \
    sa[lane] = (XV);                                                  \
    float4 L0_ = *(const float4*)&sa[0];                              \
    float4 L1_ = *(const float4*)&sa[4];                              \
    float4 L2_ = *(const float4*)&sa[8];                              \
    float4 L3_ = *(const float4*)&sa[12];                             \
    float4 L4_ = *(const float4*)&sa[16];                             \
    float4 L5_ = *(const float4*)&sa[20];                             \
    float g0_[8], g1_[8], g2_[8];                                     \
    float acc_[8];                                                    \
    _Pragma("unroll") for (int q_ = 0; q_ < 8; ++q_) acc_[q_] = 0.f;  \
    _Pragma("unroll") for (int q_ = 0; q_ < 8; ++q_) g0_[q_] = RLX(XV, 24 + q_); \
    __builtin_amdgcn_sched_barrier(0);                                \
    _Pragma("unroll") for (int q_ = 0; q_ < 8; ++q_) g1_[q_] = RLX(XV, 32 + q_); \
    _Pragma("unroll") for (int q_ = 0; q_ < 8; ++q_)                  \
      acc_[q_] = fmaf(g0_[q_], WARR[24 + q_], acc_[q_]);              \
    __builtin_amdgcn_sched_barrier(0);                                \
    _Pragma("unroll") for (int q_ = 0; q_ < 8; ++q_) g2_[q_] = RLX(XV, 40 + q_); \
    _Pragma("unroll") for (int q_ = 0; q_ < 8; ++q_)                  \
      acc_[q_] = fmaf(g1_[q_], WARR[32 + q_], acc_[q_]);              \
    __builtin_amdgcn_sched_barrier(0);                                \
    _Pragma("unroll") for (int q_ = 0; q_ < 8; ++q_)                  \
      acc_[q_] = fmaf(g2_[q_], WARR[40 + q_], acc_[q_]);              \
    LDSF(L0_, 0,  WARR); LDSF(L1_, 4,  WARR);                         \
    LDSF(L2_, 8,  WARR); LDSF(L3_, 12, WARR);                         \
    LDSF(L4_, 16, WARR); LDSF(L5_, 20, WARR);                         \
    S_OUT = ((acc_[0] + acc_[1]) + (acc_[2] + acc_[3]))               \
          + ((acc_[4] + acc_[5]) + (acc_[6] + acc_[7]));              \
    PV_OUT = L0_.x;                                                   \
  } while (0)

  if (dir == 0) {
    // ================= FORWARD: t = 1..511 =================
    float wcol[NTAGS];
#pragma unroll
    for (int i = 0; i < NTAGS; ++i)
      wcol[i] = __expf(trans[i * NTAGS + jj]);     // W[i][jj]

    float cf = 0.0f;
    float a  = __expf(start_t[jj] + emcol[0]);
    float emA[CH], emB[CH], exf;

#define FSTEP(p, CUR, NXT, T0, MASKED) do {                           \
    float s_, pv_;                                                    \
    HCORE(a, wcol, s_, pv_);                                          \
    float na_ = s_ * exf;                                             \
    if (((p) & 3) == 3) {                                             \
      float rm_ = __builtin_amdgcn_rcpf(pv_);                         \
      cf += __logf(pv_);                                              \
      if (MASKED) { int mk_ = smask[(T0) + (p)];                      \
                    a = (mk_ ? na_ : a) * rm_; }                      \
      else a = na_ * rm_;                                             \
    } else {                                                          \
      if (MASKED) { int mk_ = smask[(T0) + (p)]; a = mk_ ? na_ : a; } \
      else a = na_;                                                   \
    }                                                                 \
    exf = __expf(((p) < CH - 1) ? (CUR)[(p) + 1] : (NXT)[0]);         \
  } while (0)

#define CHUNKF(CUR, NXT, ci, PSTART, MASKED) do {                     \
    int cin_ = ((ci) + 1 < 64) ? (ci) + 1 : 63;                       \
    LOADCH(NXT, cin_);                                                \
    _Pragma("unroll")                                                 \
    for (int p_ = (PSTART); p_ < CH; ++p_)                            \
      FSTEP(p_, CUR, NXT, (ci) * CH, MASKED);                         \
  } while (0)

    LOADCH(emA, 0);
    exf = __expf(emA[1]);

#define FLOOP(M) do {                                                 \
    CHUNKF(emA, emB, 0, 1, M);                                        \
    for (int ci = 1; ci <= 61; ci += 2) {                             \
      CHUNKF(emB, emA, ci,     0, M);                                 \
      CHUNKF(emA, emB, ci + 1, 0, M);                                 \
    }                                                                 \
    CHUNKF(emB, emA, 63, 0, M);                                       \
  } while (0)

    if (allones) FLOOP(0);
    else         FLOOP(1);

    if (act) alpha[b * NTAGS + lane] = a;
    if (lane == 0) cfb[b] = cf;

  } else {
    // ================= BACKWARD: u = 1023..512 =================
    float wrow[NTAGS];
#pragma unroll
    for (int i = 0; i < NTAGS; ++i)
      wrow[i] = __expf(trans[jj * NTAGS + i]);     // W[jj][i]

    float cb = 0.0f;
    float Bv = __expf(end_t[jj]);
    float bmA[CH], bmB[CH], exb;

#define BSTEP(i, CUR, NXT, U0, MASKED) do {                           \
    const int pb_ = CH - 1 - (i);                                     \
    float gm_ = Bv * exb;                                             \
    float s_, pv_;                                                    \
    HCORE(gm_, wrow, s_, pv_);                                        \
    float nb_ = s_;                                                   \
    if (MASKED) { int mk_ = smask[(U0) + pb_]; nb_ = mk_ ? nb_ : Bv; }\
    if (((i) & 3) == 3) {                                             \
      float rm_ = __builtin_amdgcn_rcpf(pv_);                         \
      cb += __logf(pv_);                                              \
      Bv = nb_ * rm_;                                                 \
    } else Bv = nb_;                                                  \
    exb = __expf(((i) < CH - 1) ? (CUR)[pb_ - 1] : (NXT)[CH - 1]);    \
  } while (0)

#define CHUNKB(CUR, NXT, k, MASKED) do {                              \
    int kn_ = ((k) - 1 > 64) ? (k) - 1 : 64;                          \
    LOADCH(NXT, kn_);                                                 \
    _Pragma("unroll")                                                 \
    for (int i_ = 0; i_ < CH; ++i_)                                   \
      BSTEP(i_, CUR, NXT, (k) * CH, MASKED);                          \
  } while (0)

    LOADCH(bmA, 127);
    exb = __expf(bmA[CH - 1]);       // exp(em[1023])

#define BLOOP(M) do {                                                 \
    CHUNKB(bmA, bmB, 127, M);                                         \
    for (int k = 126; k >= 66; k -= 2) {                              \
      CHUNKB(bmB, bmA, k,     M);                                     \
      CHUNKB(bmA, bmB, k - 1, M);                                     \
    }                                                                 \
    CHUNKB(bmB, bmA, 64, M);                                          \
  } while (0)

    if (allones) BLOOP(0);
    else         BLOOP(1);

    if (act) beta[b * NTAGS + lane] = Bv;
    if (lane == 0) cbb[b] = cb;

    // numerator: tag-path score (moved here to balance the two directions)
    float np = 0.0f;
    int   mcount = 0;
    for (int t = lane; t < SEQ; t += 64) {
      int tag_t = tags[(size_t)t * BATCH + b];
      tag_t = min(max(tag_t, 0), NTAGS - 1);
      int mk = smask[t];
      float e = em[(size_t)t * strideT + (size_t)b * NTAGS + tag_t];
      if (t == 0) {
        np += start_t[tag_t] + e;
      } else {
        int tag_p = tags[(size_t)(t - 1) * BATCH + b];
        tag_p = min(max(tag_p, 0), NTAGS - 1);
        np += (trans[tag_p * NTAGS + tag_t] + e) * (float)mk;
      }
      mcount += (mk != 0) ? 1 : 0;
    }
#pragma unroll
    for (int off = 32; off > 0; off >>= 1) {
      np     += __shfl_xor(np, off);
      mcount += __shfl_xor(mcount, off);
    }
    int last_idx = min(max(mcount - 1, 0), SEQ - 1);
    int tag_last = tags[(size_t)last_idx * BATCH + b];
    tag_last = min(max(tag_last, 0), NTAGS - 1);
    if (lane == 0) numb[b] = np + end_t[tag_last];
  }
}

// 512 threads, one per chain: den = cf+cb+log(alpha.beta); mean of num-den.
__global__ __launch_bounds__(512) void crf_combine_kernel(
    const float* __restrict__ alpha, const float* __restrict__ beta,
    const float* __restrict__ cfb,   const float* __restrict__ cbb,
    const float* __restrict__ numb,  float* __restrict__ out)
{
  const int tid = threadIdx.x;       // 0..511 = chain
  float dot = 0.0f;
#pragma unroll
  for (int j = 0; j < NTAGS; j += 4) {
    float4 av = *(const float4*)&alpha[tid * NTAGS + j];
    float4 bv = *(const float4*)&beta [tid * NTAGS + j];
    dot += av.x * bv.x + av.y * bv.y + av.z * bv.z + av.w * bv.w;
  }
  float den = cfb[tid] + cbb[tid] + __logf(dot);
  float v   = numb[tid] - den;

#pragma unroll
  for (int off = 32; off > 0; off >>= 1)
    v += __shfl_xor(v, off);

  __shared__ float sw[8];
  if ((tid & 63) == 0) sw[tid >> 6] = v;
  __syncthreads();
  if (tid == 0) {
    float s = 0.0f;
#pragma unroll
    for (int w = 0; w < 8; ++w) s += sw[w];
    out[0] = s * (1.0f / (float)BATCH);
  }
}

extern "C" void kernel_launch(void* const* d_in, const int* in_sizes, int n_in,
                              void* d_out, int out_size, void* d_ws, size_t ws_size,
                              hipStream_t stream) {
  const float* em   = (const float*)d_in[0];
  const int*   tg   = (const int*)  d_in[1];
  const int*   mask = (const int*)  d_in[2];
  const float* st   = (const float*)d_in[3];
  const float* en   = (const float*)d_in[4];
  const float* tr   = (const float*)d_in[5];

  float* ws    = (float*)d_ws;
  float* alpha = ws;                              // 512*48
  float* beta  = ws + BATCH * NTAGS;              // 512*48
  float* cfb   = ws + 2 * BATCH * NTAGS;          // 512
  float* cbb   = cfb + BATCH;                     // 512
  float* numb  = cbb + BATCH;                     // 512

  crf_dir_kernel<<<2 * BATCH, 64, 0, stream>>>(em, tg, mask, st, en, tr,
                                               alpha, beta, cfb, cbb, numb);
  crf_combine_kernel<<<1, 512, 0, stream>>>(alpha, beta, cfb, cbb, numb,
                                            (float*)d_out);
}